// Round 4
// baseline (694.252 us; speedup 1.0000x reference)
//
#include <hip/hip_runtime.h>
#include <hip/hip_bf16.h>

#define D 768
#define NH 12
#define HD 64
#define BATCH 4
#define LSEQ 8190
#define LPAD 8192
#define TP (BATCH*LPAD)      /* 32768 padded tokens */

typedef __bf16 bf16x8 __attribute__((ext_vector_type(8)));
typedef __bf16 bf16x4 __attribute__((ext_vector_type(4)));
typedef float f32x4 __attribute__((ext_vector_type(4)));
using bf16 = __hip_bfloat16;

__device__ __forceinline__ float b2f(bf16 x){ return __bfloat162float(x); }
__device__ __forceinline__ bf16 f2b(float x){ return __float2bfloat16(x); }
__device__ __forceinline__ f32x4 mfma16(bf16x8 a, bf16x8 b, f32x4 c){
    return __builtin_amdgcn_mfma_f32_16x16x32_bf16(a, b, c, 0, 0, 0);
}

// ---------------------------------------------------------------------------
// Transpose+convert 768x768 fp32 weights into bf16 [n][k] layout.
// ---------------------------------------------------------------------------
__global__ void k_transpose(const float* __restrict__ w0, const float* __restrict__ w1,
                            const float* __restrict__ w2, const float* __restrict__ w3,
                            bf16* __restrict__ t0, bf16* __restrict__ t1,
                            bf16* __restrict__ t2, bf16* __restrict__ t3) {
    const float* src; bf16* dst;
    switch (blockIdx.y) {
        case 0:  src = w0; dst = t0; break;
        case 1:  src = w1; dst = t1; break;
        case 2:  src = w2; dst = t2; break;
        default: src = w3; dst = t3; break;
    }
    int o = blockIdx.x * 256 + threadIdx.x;   // 0..589823
    int n = o / D, k = o % D;
    dst[o] = f2b(src[k * D + n]);             // dst[n][k] = src[k][n]
}

// ---------------------------------------------------------------------------
// QKV projection GEMM for one token chunk. blockIdx.z selects Q/K/V.
// X fp32 (global padded-token indexed; pad rows -> zeros); W bf16 [n][k];
// fp32 MFMA accumulate; outputs bf16, chunk-local rows.
// LDS row stride 40 bf16 = 80 B (16B-aligned, only free 2-way bank aliasing).
// ---------------------------------------------------------------------------
__global__ __launch_bounds__(256) void k_qkv(
    const float* __restrict__ X,
    const bf16* __restrict__ WqT, const bf16* __restrict__ WkT, const bf16* __restrict__ WvT,
    const float* __restrict__ bq, const float* __restrict__ bk, const float* __restrict__ bv,
    bf16* __restrict__ Qb, bf16* __restrict__ Kb, bf16* __restrict__ Vb, int tok0)
{
    __shared__ bf16 a_lds[128 * 40];
    __shared__ bf16 b_lds[128 * 40];
    const bf16* Bt; const float* bias; bf16* Cout;
    if (blockIdx.z == 0)      { Bt = WqT; bias = bq; Cout = Qb; }
    else if (blockIdx.z == 1) { Bt = WkT; bias = bk; Cout = Kb; }
    else                      { Bt = WvT; bias = bv; Cout = Vb; }

    const int tid = threadIdx.x;
    const int rt = blockIdx.x, ct = blockIdx.y;
    const int wave = tid >> 6, lane = tid & 63, quad = lane >> 4, lm = lane & 15;
    const int wm = wave >> 1, wn = wave & 1;

    f32x4 acc[4][4] = {};

    for (int kt = 0; kt < D / 32; ++kt) {
        // A tile 128x32 fp32 -> bf16: 4 passes x 256 threads x float4
        #pragma unroll
        for (int p = 0; p < 4; ++p) {
            int cid = tid + p * 256;          // 0..1023
            int row = cid >> 3, kc = (cid & 7) * 4;
            int g = tok0 + rt * 128 + row;
            int b = g >> 13, pos = g & 8191;
            float4 va = {0.f, 0.f, 0.f, 0.f};
            if (pos < LSEQ)
                va = *reinterpret_cast<const float4*>(&X[((size_t)b * LSEQ + pos) * D + kt * 32 + kc]);
            bf16x4 vb; vb[0] = (__bf16)f2b(va.x); vb[1] = (__bf16)f2b(va.y);
            vb[2] = (__bf16)f2b(va.z); vb[3] = (__bf16)f2b(va.w);
            *reinterpret_cast<bf16x4*>(&a_lds[row * 40 + kc]) = vb;
        }
        // B tile 128x32 bf16: 2 passes x 256 threads x 16B
        #pragma unroll
        for (int p = 0; p < 2; ++p) {
            int cid = tid + p * 256;          // 0..511
            int row = cid >> 2, kc = (cid & 3) * 8;
            *reinterpret_cast<uint4*>(&b_lds[row * 40 + kc]) =
                *reinterpret_cast<const uint4*>(&Bt[(size_t)(ct * 128 + row) * D + kt * 32 + kc]);
        }
        __syncthreads();
        bf16x8 af[4], bfr[4];
        #pragma unroll
        for (int i = 0; i < 4; ++i)
            af[i] = *reinterpret_cast<const bf16x8*>(&a_lds[(wm * 64 + i * 16 + lm) * 40 + quad * 8]);
        #pragma unroll
        for (int n = 0; n < 4; ++n)
            bfr[n] = *reinterpret_cast<const bf16x8*>(&b_lds[(wn * 64 + n * 16 + lm) * 40 + quad * 8]);
        #pragma unroll
        for (int i = 0; i < 4; ++i)
            #pragma unroll
            for (int n = 0; n < 4; ++n)
                acc[i][n] = mfma16(af[i], bfr[n], acc[i][n]);
        __syncthreads();
    }

    float bvv[4];
    #pragma unroll
    for (int n = 0; n < 4; ++n)
        bvv[n] = bias[ct * 128 + wn * 64 + n * 16 + lm];

    #pragma unroll
    for (int i = 0; i < 4; ++i)
        #pragma unroll
        for (int reg = 0; reg < 4; ++reg) {
            int lrow = rt * 128 + wm * 64 + i * 16 + quad * 4 + reg;   // chunk-local
            #pragma unroll
            for (int n = 0; n < 4; ++n) {
                int col = ct * 128 + wn * 64 + n * 16 + lm;
                Cout[(size_t)lrow * D + col] = f2b(acc[i][n][reg] + bvv[n]);
            }
        }
}

// ---------------------------------------------------------------------------
// Output projection + bias + fp32 residual, cropped into fp32 d_out.
// A (attn out) bf16 chunk-local; W bf16 [n][k].
// ---------------------------------------------------------------------------
__global__ __launch_bounds__(256) void k_oproj(
    const bf16* __restrict__ A, const bf16* __restrict__ WoT,
    const float* __restrict__ bo, const float* __restrict__ X,
    float* __restrict__ out, int tok0)
{
    __shared__ bf16 a_lds[128 * 40];
    __shared__ bf16 b_lds[128 * 40];
    const int tid = threadIdx.x;
    const int rt = blockIdx.x, ct = blockIdx.y;
    const int wave = tid >> 6, lane = tid & 63, quad = lane >> 4, lm = lane & 15;
    const int wm = wave >> 1, wn = wave & 1;

    f32x4 acc[4][4] = {};

    for (int kt = 0; kt < D / 32; ++kt) {
        #pragma unroll
        for (int p = 0; p < 2; ++p) {
            int cid = tid + p * 256;
            int row = cid >> 2, kc = (cid & 3) * 8;
            *reinterpret_cast<uint4*>(&a_lds[row * 40 + kc]) =
                *reinterpret_cast<const uint4*>(&A[(size_t)(rt * 128 + row) * D + kt * 32 + kc]);
            *reinterpret_cast<uint4*>(&b_lds[row * 40 + kc]) =
                *reinterpret_cast<const uint4*>(&WoT[(size_t)(ct * 128 + row) * D + kt * 32 + kc]);
        }
        __syncthreads();
        bf16x8 af[4], bfr[4];
        #pragma unroll
        for (int i = 0; i < 4; ++i)
            af[i] = *reinterpret_cast<const bf16x8*>(&a_lds[(wm * 64 + i * 16 + lm) * 40 + quad * 8]);
        #pragma unroll
        for (int n = 0; n < 4; ++n)
            bfr[n] = *reinterpret_cast<const bf16x8*>(&b_lds[(wn * 64 + n * 16 + lm) * 40 + quad * 8]);
        #pragma unroll
        for (int i = 0; i < 4; ++i)
            #pragma unroll
            for (int n = 0; n < 4; ++n)
                acc[i][n] = mfma16(af[i], bfr[n], acc[i][n]);
        __syncthreads();
    }

    float bvv[4];
    #pragma unroll
    for (int n = 0; n < 4; ++n)
        bvv[n] = bo[ct * 128 + wn * 64 + n * 16 + lm];

    #pragma unroll
    for (int i = 0; i < 4; ++i)
        #pragma unroll
        for (int reg = 0; reg < 4; ++reg) {
            int g = tok0 + rt * 128 + wm * 64 + i * 16 + quad * 4 + reg;
            int b = g >> 13, pos = g & 8191;
            if (pos >= LSEQ) continue;           // crop pad rows
            size_t orow = (size_t)b * LSEQ + pos;
            #pragma unroll
            for (int n = 0; n < 4; ++n) {
                int col = ct * 128 + wn * 64 + n * 16 + lm;
                out[orow * D + col] = acc[i][n][reg] + bvv[n] + X[orow * D + col];
            }
        }
}

// ---------------------------------------------------------------------------
// Per-(window, head) attention on bf16 buffers: S=QK^T, softmax/8, O=PV.
// QO alias safe: block reads Q slice fully before overwriting same slice.
// LDS: Q(128x72) | K(128x72); P(128x136) overlays both after barrier.
// All strides x2B are 16B multiples (144/272 B) -> aligned b128 access.
// ---------------------------------------------------------------------------
__global__ __launch_bounds__(256) void k_attn(
    bf16* QO, const bf16* __restrict__ K, const bf16* __restrict__ V)
{
    __shared__ bf16 qk_lds[2 * 128 * 72];
    __shared__ bf16 vt_lds[64 * 136];
    const int tid = threadIdx.x;
    const int g0 = blockIdx.x * 128, hc = blockIdx.y * 64;
    const int wave = tid >> 6, lane = tid & 63, quad = lane >> 4, lm = lane & 15;
    const int wq = wave * 32;
    bf16* Q_lds = qk_lds;
    bf16* K_lds = qk_lds + 128 * 72;
    bf16* P_lds = qk_lds;                   // overlay after barrier, stride 136

    #pragma unroll
    for (int p = 0; p < 4; ++p) {
        int cid = tid + p * 256;            // 0..1023
        int r = cid >> 3, cc = (cid & 7) * 8;
        *reinterpret_cast<uint4*>(&Q_lds[r * 72 + cc]) =
            *reinterpret_cast<const uint4*>(&QO[(size_t)(g0 + r) * D + hc + cc]);
        *reinterpret_cast<uint4*>(&K_lds[r * 72 + cc]) =
            *reinterpret_cast<const uint4*>(&K[(size_t)(g0 + r) * D + hc + cc]);
        uint4 vv = *reinterpret_cast<const uint4*>(&V[(size_t)(g0 + r) * D + hc + cc]);
        const bf16* ve = reinterpret_cast<const bf16*>(&vv);
        #pragma unroll
        for (int j = 0; j < 8; ++j) vt_lds[(cc + j) * 136 + r] = ve[j];   // V^T
    }
    __syncthreads();

    // S = Q K^T : each wave computes 32 query rows x 128 keys
    f32x4 s[2][8] = {};
    #pragma unroll
    for (int ks = 0; ks < HD; ks += 32) {
        bf16x8 aq[2];
        #pragma unroll
        for (int i = 0; i < 2; ++i)
            aq[i] = *reinterpret_cast<const bf16x8*>(&Q_lds[(wq + i * 16 + lm) * 72 + ks + quad * 8]);
        #pragma unroll
        for (int nt = 0; nt < 8; ++nt) {
            bf16x8 bk = *reinterpret_cast<const bf16x8*>(&K_lds[(nt * 16 + lm) * 72 + ks + quad * 8]);
            s[0][nt] = mfma16(aq[0], bk, s[0][nt]);
            s[1][nt] = mfma16(aq[1], bk, s[1][nt]);
        }
    }
    __syncthreads();   // all Q/K reads done before P overlays them

    // softmax rows (row = wq + i*16 + quad*4 + reg); scale = 1/sqrt(64)
    const float scale = 0.125f;
    #pragma unroll
    for (int i = 0; i < 2; ++i)
        #pragma unroll
        for (int reg = 0; reg < 4; ++reg) {
            float m = -1e30f;
            #pragma unroll
            for (int nt = 0; nt < 8; ++nt) m = fmaxf(m, s[i][nt][reg]);
            #pragma unroll
            for (int off = 8; off >= 1; off >>= 1) m = fmaxf(m, __shfl_xor(m, off));
            float pv[8]; float sum = 0.f;
            #pragma unroll
            for (int nt = 0; nt < 8; ++nt) {
                float p = __expf((s[i][nt][reg] - m) * scale);
                pv[nt] = p; sum += p;
            }
            #pragma unroll
            for (int off = 8; off >= 1; off >>= 1) sum += __shfl_xor(sum, off);
            float rinv = 1.f / sum;
            int row = wq + i * 16 + quad * 4 + reg;
            #pragma unroll
            for (int nt = 0; nt < 8; ++nt)
                P_lds[row * 136 + nt * 16 + lm] = f2b(pv[nt] * rinv);
        }
    __syncthreads();

    // O = P V : 32 query rows x 64 head dims per wave
    f32x4 o[2][4] = {};
    #pragma unroll
    for (int ks = 0; ks < 128; ks += 32) {
        bf16x8 ap[2];
        #pragma unroll
        for (int i = 0; i < 2; ++i)
            ap[i] = *reinterpret_cast<const bf16x8*>(&P_lds[(wq + i * 16 + lm) * 136 + ks + quad * 8]);
        #pragma unroll
        for (int n = 0; n < 4; ++n) {
            bf16x8 bv = *reinterpret_cast<const bf16x8*>(&vt_lds[(n * 16 + lm) * 136 + ks + quad * 8]);
            o[0][n] = mfma16(ap[0], bv, o[0][n]);
            o[1][n] = mfma16(ap[1], bv, o[1][n]);
        }
    }
    #pragma unroll
    for (int i = 0; i < 2; ++i)
        #pragma unroll
        for (int reg = 0; reg < 4; ++reg) {
            int row = wq + i * 16 + quad * 4 + reg;
            #pragma unroll
            for (int n = 0; n < 4; ++n)
                QO[(size_t)(g0 + row) * D + hc + n * 16 + lm] = f2b(o[i][n][reg]);
        }
}

// ---------------------------------------------------------------------------
// In-place fp32 LayerNorm.
// ---------------------------------------------------------------------------
__global__ __launch_bounds__(256) void k_ln(const float* __restrict__ g_,
                                            const float* __restrict__ b_,
                                            float* __restrict__ y)
{
    __shared__ float red[256];
    const size_t base = (size_t)blockIdx.x * D;
    const int tid = threadIdx.x;
    float v[3];
    #pragma unroll
    for (int j = 0; j < 3; ++j) v[j] = y[base + tid + j * 256];

    red[tid] = v[0] + v[1] + v[2];
    __syncthreads();
    for (int o = 128; o > 0; o >>= 1) {
        if (tid < o) red[tid] += red[tid + o];
        __syncthreads();
    }
    float mu = red[0] * (1.f / 768.f);
    __syncthreads();

    float d0 = v[0] - mu, d1 = v[1] - mu, d2 = v[2] - mu;
    red[tid] = d0 * d0 + d1 * d1 + d2 * d2;
    __syncthreads();
    for (int o = 128; o > 0; o >>= 1) {
        if (tid < o) red[tid] += red[tid + o];
        __syncthreads();
    }
    float var = red[0] * (1.f / 768.f);
    float r = rsqrtf(var + 1e-5f);

    #pragma unroll
    for (int j = 0; j < 3; ++j) {
        int c = tid + j * 256;
        y[base + c] = (v[j] - mu) * r * g_[c] + b_[c];
    }
}

// ---------------------------------------------------------------------------
extern "C" void kernel_launch(void* const* d_in, const int* in_sizes, int n_in,
                              void* d_out, int out_size, void* d_ws, size_t ws_size,
                              hipStream_t stream)
{
    const float* expanded = (const float*)d_in[0];
    const float* Wq = (const float*)d_in[1];
    const float* bq = (const float*)d_in[2];
    const float* Wk = (const float*)d_in[3];
    const float* bk = (const float*)d_in[4];
    const float* Wv = (const float*)d_in[5];
    const float* bv = (const float*)d_in[6];
    const float* Wo = (const float*)d_in[7];
    const float* bo = (const float*)d_in[8];
    const float* ln_g = (const float*)d_in[9];
    const float* ln_b = (const float*)d_in[10];
    float* out = (float*)d_out;

    char* ws = (char*)d_ws;
    const size_t WSZ = (size_t)D * D * sizeof(bf16);     // 1.18 MB (bf16)
    bf16* WqT = (bf16*)(ws);
    bf16* WkT = (bf16*)(ws + WSZ);
    bf16* WvT = (bf16*)(ws + 2 * WSZ);
    bf16* WoT = (bf16*)(ws + 3 * WSZ);
    const size_t base = 4 * WSZ;

    // Largest token-chunk whose bf16 Q/K/V fit the workspace (ws_size is
    // constant across calls -> identical launch sequence every call).
    int cht = TP;
    while (cht > 128 && base + 3 * (size_t)cht * D * sizeof(bf16) > ws_size)
        cht >>= 1;
    const size_t CSZ = (size_t)cht * D * sizeof(bf16);
    bf16* Qb = (bf16*)(ws + base);            // attention output aliases Qb
    bf16* Kb = (bf16*)(ws + base + CSZ);
    bf16* Vb = (bf16*)(ws + base + 2 * CSZ);

    k_transpose<<<dim3((D * D) / 256, 4), 256, 0, stream>>>(Wq, Wk, Wv, Wo, WqT, WkT, WvT, WoT);

    for (int t0 = 0; t0 < TP; t0 += cht) {
        k_qkv<<<dim3(cht / 128, D / 128, 3), 256, 0, stream>>>(
            expanded, WqT, WkT, WvT, bq, bk, bv, Qb, Kb, Vb, t0);
        k_attn<<<dim3(cht / 128, NH), 256, 0, stream>>>(Qb, Kb, Vb);
        k_oproj<<<dim3(cht / 128, D / 128), 256, 0, stream>>>(Qb, WoT, bo, expanded, out, t0);
    }

    k_ln<<<BATCH * LSEQ, 256, 0, stream>>>(ln_g, ln_b, out);
}

// Round 5
// 532.243 us; speedup vs baseline: 1.3044x; 1.3044x over previous
//
#include <hip/hip_runtime.h>
#include <hip/hip_bf16.h>

#define D 768
#define NQKV 2304            /* 3*D */
#define NH 12
#define HD 64
#define BATCH 4
#define LSEQ 8190
#define LPAD 8192
#define TP (BATCH*LPAD)      /* 32768 padded tokens */

typedef __bf16 bf16x8 __attribute__((ext_vector_type(8)));
typedef float f32x4 __attribute__((ext_vector_type(4)));
using bf16 = __hip_bfloat16;

__device__ __forceinline__ float b2f(bf16 x){ return __bfloat162float(x); }
__device__ __forceinline__ bf16 f2b(float x){ return __float2bfloat16(x); }
__device__ __forceinline__ f32x4 mfma16(bf16x8 a, bf16x8 b, f32x4 c){
    return __builtin_amdgcn_mfma_f32_16x16x32_bf16(a, b, c, 0, 0, 0);
}
// async global->LDS, 16 B per lane; LDS dest = wave-uniform base + lane*16
__device__ __forceinline__ void gload_lds16(const void* g, void* l){
    __builtin_amdgcn_global_load_lds(
        (const __attribute__((address_space(1))) unsigned int*)g,
        (__attribute__((address_space(3))) unsigned int*)l, 16, 0, 0);
}

// ---------------------------------------------------------------------------
// Transpose+convert fp32 weights -> bf16 [n][k]. y=0..2 -> WqkvT slices, y=3 -> WoT.
// ---------------------------------------------------------------------------
__global__ void k_transpose(const float* __restrict__ w0, const float* __restrict__ w1,
                            const float* __restrict__ w2, const float* __restrict__ w3,
                            bf16* __restrict__ WqkvT, bf16* __restrict__ WoT) {
    const float* src; bf16* dst;
    switch (blockIdx.y) {
        case 0:  src = w0; dst = WqkvT;               break;
        case 1:  src = w1; dst = WqkvT + D * D;       break;
        case 2:  src = w2; dst = WqkvT + 2 * D * D;   break;
        default: src = w3; dst = WoT;                 break;
    }
    int o = blockIdx.x * 256 + threadIdx.x;   // 0..589823
    int n = o / D, k = o % D;
    dst[o] = f2b(src[k * D + n]);             // dst[n][k] = src[k][n]
}

// ---------------------------------------------------------------------------
// Convert chunk of X (global padded-token indexed) to bf16, pad rows -> 0.
// 8 elems per thread, fully coalesced.
// ---------------------------------------------------------------------------
__global__ __launch_bounds__(256) void k_prep(const float* __restrict__ X,
                                              bf16* __restrict__ Xb, int tok0)
{
    int idx = (blockIdx.x * 256 + threadIdx.x) * 8;  // chunk-local elem
    int row = idx / D, col = idx % D;
    int gt = tok0 + row, b = gt >> 13, pos = gt & 8191;
    bf16 tmp[8];
    if (pos < LSEQ) {
        const float* s = &X[((size_t)b * LSEQ + pos) * D + col];
        float4 f0 = *reinterpret_cast<const float4*>(s);
        float4 f1 = *reinterpret_cast<const float4*>(s + 4);
        tmp[0]=f2b(f0.x); tmp[1]=f2b(f0.y); tmp[2]=f2b(f0.z); tmp[3]=f2b(f0.w);
        tmp[4]=f2b(f1.x); tmp[5]=f2b(f1.y); tmp[6]=f2b(f1.z); tmp[7]=f2b(f1.w);
    } else {
        #pragma unroll
        for (int j = 0; j < 8; ++j) tmp[j] = f2b(0.f);
    }
    *reinterpret_cast<uint4*>(&Xb[idx]) = *reinterpret_cast<const uint4*>(tmp);
}

// ---------------------------------------------------------------------------
// Fused QKV GEMM (m97 structure): C[cht x 2304] = Xb[cht x 768] * WqkvT^T + b.
// 128x128 tile, BK=32, global_load_lds 16B staging, unpadded LDS (stride 32).
// Output bf16 rows chunk-local, row stride 2304.
// ---------------------------------------------------------------------------
__global__ __launch_bounds__(256) void k_gemm_qkv(
    const bf16* __restrict__ Xb, const bf16* __restrict__ Wt,
    const float* __restrict__ bq, const float* __restrict__ bk, const float* __restrict__ bv,
    bf16* __restrict__ Qkv)
{
    __shared__ bf16 a_lds[128 * 32];
    __shared__ bf16 b_lds[128 * 32];
    const int tid = threadIdx.x;
    const int rt = blockIdx.x, ct = blockIdx.y;
    const int wave = tid >> 6, lane = tid & 63, quad = lane >> 4, lm = lane & 15;
    const int wm = wave >> 1, wn = wave & 1;
    const int seg0 = wave * 2, seg1 = seg0 + 1;      // 16-row LDS segments
    const int srow = lane >> 2, selem = (lane & 3) * 8;

    const bf16* Ag = Xb + (size_t)(rt * 128) * D;
    const bf16* Bg = Wt + (size_t)(ct * 128) * D;

    f32x4 acc[4][4] = {};

    for (int kt = 0; kt < D; kt += 32) {
        gload_lds16(Ag + (size_t)(seg0 * 16 + srow) * D + kt + selem, &a_lds[seg0 * 512]);
        gload_lds16(Ag + (size_t)(seg1 * 16 + srow) * D + kt + selem, &a_lds[seg1 * 512]);
        gload_lds16(Bg + (size_t)(seg0 * 16 + srow) * D + kt + selem, &b_lds[seg0 * 512]);
        gload_lds16(Bg + (size_t)(seg1 * 16 + srow) * D + kt + selem, &b_lds[seg1 * 512]);
        __syncthreads();
        bf16x8 af[4], bfr[4];
        #pragma unroll
        for (int i = 0; i < 4; ++i)
            af[i] = *reinterpret_cast<const bf16x8*>(&a_lds[(wm * 64 + i * 16 + lm) * 32 + quad * 8]);
        #pragma unroll
        for (int n = 0; n < 4; ++n)
            bfr[n] = *reinterpret_cast<const bf16x8*>(&b_lds[(wn * 64 + n * 16 + lm) * 32 + quad * 8]);
        #pragma unroll
        for (int i = 0; i < 4; ++i)
            #pragma unroll
            for (int n = 0; n < 4; ++n)
                acc[i][n] = mfma16(af[i], bfr[n], acc[i][n]);
        __syncthreads();
    }

    // bias: ct*128 block lies entirely inside one of q/k/v (768 % 128 == 0)
    const float* bias = (ct < 6) ? bq : (ct < 12 ? bk : bv);
    const int cb = ct * 128 - (ct < 6 ? 0 : (ct < 12 ? D : 2 * D));
    float bvv[4];
    #pragma unroll
    for (int n = 0; n < 4; ++n)
        bvv[n] = bias[cb + wn * 64 + n * 16 + lm];

    #pragma unroll
    for (int i = 0; i < 4; ++i)
        #pragma unroll
        for (int reg = 0; reg < 4; ++reg) {
            int lrow = rt * 128 + wm * 64 + i * 16 + quad * 4 + reg;
            #pragma unroll
            for (int n = 0; n < 4; ++n) {
                int col = ct * 128 + wn * 64 + n * 16 + lm;
                Qkv[(size_t)lrow * NQKV + col] = f2b(acc[i][n][reg] + bvv[n]);
            }
        }
}

// ---------------------------------------------------------------------------
// Output projection (m97 structure) + bias + fp32 residual -> fp32 d_out.
// A = attention output living in the Q slice of Qkv (row stride 2304).
// ---------------------------------------------------------------------------
__global__ __launch_bounds__(256) void k_oproj(
    const bf16* __restrict__ Aq, const bf16* __restrict__ WoT,
    const float* __restrict__ bo, const float* __restrict__ X,
    float* __restrict__ out, int tok0)
{
    __shared__ bf16 a_lds[128 * 32];
    __shared__ bf16 b_lds[128 * 32];
    const int tid = threadIdx.x;
    const int rt = blockIdx.x, ct = blockIdx.y;
    const int wave = tid >> 6, lane = tid & 63, quad = lane >> 4, lm = lane & 15;
    const int wm = wave >> 1, wn = wave & 1;
    const int seg0 = wave * 2, seg1 = seg0 + 1;
    const int srow = lane >> 2, selem = (lane & 3) * 8;

    const bf16* Ag = Aq + (size_t)(rt * 128) * NQKV;   // O in Q slice, stride 2304
    const bf16* Bg = WoT + (size_t)(ct * 128) * D;

    f32x4 acc[4][4] = {};

    for (int kt = 0; kt < D; kt += 32) {
        gload_lds16(Ag + (size_t)(seg0 * 16 + srow) * NQKV + kt + selem, &a_lds[seg0 * 512]);
        gload_lds16(Ag + (size_t)(seg1 * 16 + srow) * NQKV + kt + selem, &a_lds[seg1 * 512]);
        gload_lds16(Bg + (size_t)(seg0 * 16 + srow) * D + kt + selem, &b_lds[seg0 * 512]);
        gload_lds16(Bg + (size_t)(seg1 * 16 + srow) * D + kt + selem, &b_lds[seg1 * 512]);
        __syncthreads();
        bf16x8 af[4], bfr[4];
        #pragma unroll
        for (int i = 0; i < 4; ++i)
            af[i] = *reinterpret_cast<const bf16x8*>(&a_lds[(wm * 64 + i * 16 + lm) * 32 + quad * 8]);
        #pragma unroll
        for (int n = 0; n < 4; ++n)
            bfr[n] = *reinterpret_cast<const bf16x8*>(&b_lds[(wn * 64 + n * 16 + lm) * 32 + quad * 8]);
        #pragma unroll
        for (int i = 0; i < 4; ++i)
            #pragma unroll
            for (int n = 0; n < 4; ++n)
                acc[i][n] = mfma16(af[i], bfr[n], acc[i][n]);
        __syncthreads();
    }

    float bvv[4];
    #pragma unroll
    for (int n = 0; n < 4; ++n)
        bvv[n] = bo[ct * 128 + wn * 64 + n * 16 + lm];

    #pragma unroll
    for (int i = 0; i < 4; ++i)
        #pragma unroll
        for (int reg = 0; reg < 4; ++reg) {
            int g = tok0 + rt * 128 + wm * 64 + i * 16 + quad * 4 + reg;
            int b = g >> 13, pos = g & 8191;
            if (pos >= LSEQ) continue;           // crop pad rows
            size_t orow = (size_t)b * LSEQ + pos;
            #pragma unroll
            for (int n = 0; n < 4; ++n) {
                int col = ct * 128 + wn * 64 + n * 16 + lm;
                out[orow * D + col] = acc[i][n][reg] + bvv[n] + X[orow * D + col];
            }
        }
}

// ---------------------------------------------------------------------------
// Per-(window, head) attention on the interleaved Qkv buffer (stride 2304).
// Q cols [0,768), K [768,1536), V [1536,2304). O overwrites the Q slice
// (block reads its Q slice fully before writing - safe).
// ---------------------------------------------------------------------------
__global__ __launch_bounds__(256) void k_attn(bf16* Qkv)
{
    __shared__ bf16 qk_lds[2 * 128 * 72];
    __shared__ bf16 vt_lds[64 * 136];
    const int tid = threadIdx.x;
    const int g0 = blockIdx.x * 128, hc = blockIdx.y * 64;
    const int wave = tid >> 6, lane = tid & 63, quad = lane >> 4, lm = lane & 15;
    const int wq = wave * 32;
    bf16* Q_lds = qk_lds;
    bf16* K_lds = qk_lds + 128 * 72;
    bf16* P_lds = qk_lds;                   // overlay after barrier, stride 136

    #pragma unroll
    for (int p = 0; p < 4; ++p) {
        int cid = tid + p * 256;            // 0..1023
        int r = cid >> 3, cc = (cid & 7) * 8;
        size_t rb = (size_t)(g0 + r) * NQKV;
        *reinterpret_cast<uint4*>(&Q_lds[r * 72 + cc]) =
            *reinterpret_cast<const uint4*>(&Qkv[rb + hc + cc]);
        *reinterpret_cast<uint4*>(&K_lds[r * 72 + cc]) =
            *reinterpret_cast<const uint4*>(&Qkv[rb + D + hc + cc]);
        uint4 vv = *reinterpret_cast<const uint4*>(&Qkv[rb + 2 * D + hc + cc]);
        const bf16* ve = reinterpret_cast<const bf16*>(&vv);
        #pragma unroll
        for (int j = 0; j < 8; ++j) vt_lds[(cc + j) * 136 + r] = ve[j];   // V^T
    }
    __syncthreads();

    // S = Q K^T : each wave computes 32 query rows x 128 keys
    f32x4 s[2][8] = {};
    #pragma unroll
    for (int ks = 0; ks < HD; ks += 32) {
        bf16x8 aq[2];
        #pragma unroll
        for (int i = 0; i < 2; ++i)
            aq[i] = *reinterpret_cast<const bf16x8*>(&Q_lds[(wq + i * 16 + lm) * 72 + ks + quad * 8]);
        #pragma unroll
        for (int nt = 0; nt < 8; ++nt) {
            bf16x8 bk = *reinterpret_cast<const bf16x8*>(&K_lds[(nt * 16 + lm) * 72 + ks + quad * 8]);
            s[0][nt] = mfma16(aq[0], bk, s[0][nt]);
            s[1][nt] = mfma16(aq[1], bk, s[1][nt]);
        }
    }
    __syncthreads();   // all Q/K reads done before P overlays them

    const float scale = 0.125f;             // 1/sqrt(64)
    #pragma unroll
    for (int i = 0; i < 2; ++i)
        #pragma unroll
        for (int reg = 0; reg < 4; ++reg) {
            float m = -1e30f;
            #pragma unroll
            for (int nt = 0; nt < 8; ++nt) m = fmaxf(m, s[i][nt][reg]);
            #pragma unroll
            for (int off = 8; off >= 1; off >>= 1) m = fmaxf(m, __shfl_xor(m, off));
            float pv[8]; float sum = 0.f;
            #pragma unroll
            for (int nt = 0; nt < 8; ++nt) {
                float p = __expf((s[i][nt][reg] - m) * scale);
                pv[nt] = p; sum += p;
            }
            #pragma unroll
            for (int off = 8; off >= 1; off >>= 1) sum += __shfl_xor(sum, off);
            float rinv = 1.f / sum;
            int row = wq + i * 16 + quad * 4 + reg;
            #pragma unroll
            for (int nt = 0; nt < 8; ++nt)
                P_lds[row * 136 + nt * 16 + lm] = f2b(pv[nt] * rinv);
        }
    __syncthreads();

    // O = P V
    f32x4 o[2][4] = {};
    #pragma unroll
    for (int ks = 0; ks < 128; ks += 32) {
        bf16x8 ap[2];
        #pragma unroll
        for (int i = 0; i < 2; ++i)
            ap[i] = *reinterpret_cast<const bf16x8*>(&P_lds[(wq + i * 16 + lm) * 136 + ks + quad * 8]);
        #pragma unroll
        for (int n = 0; n < 4; ++n) {
            bf16x8 bv = *reinterpret_cast<const bf16x8*>(&vt_lds[(n * 16 + lm) * 136 + ks + quad * 8]);
            o[0][n] = mfma16(ap[0], bv, o[0][n]);
            o[1][n] = mfma16(ap[1], bv, o[1][n]);
        }
    }
    #pragma unroll
    for (int i = 0; i < 2; ++i)
        #pragma unroll
        for (int reg = 0; reg < 4; ++reg) {
            int row = wq + i * 16 + quad * 4 + reg;
            #pragma unroll
            for (int n = 0; n < 4; ++n)
                Qkv[(size_t)(g0 + row) * NQKV + hc + n * 16 + lm] = f2b(o[i][n][reg]);
        }
}

// ---------------------------------------------------------------------------
// In-place fp32 LayerNorm.
// ---------------------------------------------------------------------------
__global__ __launch_bounds__(256) void k_ln(const float* __restrict__ g_,
                                            const float* __restrict__ b_,
                                            float* __restrict__ y)
{
    __shared__ float red[256];
    const size_t base = (size_t)blockIdx.x * D;
    const int tid = threadIdx.x;
    float v[3];
    #pragma unroll
    for (int j = 0; j < 3; ++j) v[j] = y[base + tid + j * 256];

    red[tid] = v[0] + v[1] + v[2];
    __syncthreads();
    for (int o = 128; o > 0; o >>= 1) {
        if (tid < o) red[tid] += red[tid + o];
        __syncthreads();
    }
    float mu = red[0] * (1.f / 768.f);
    __syncthreads();

    float d0 = v[0] - mu, d1 = v[1] - mu, d2 = v[2] - mu;
    red[tid] = d0 * d0 + d1 * d1 + d2 * d2;
    __syncthreads();
    for (int o = 128; o > 0; o >>= 1) {
        if (tid < o) red[tid] += red[tid + o];
        __syncthreads();
    }
    float var = red[0] * (1.f / 768.f);
    float r = rsqrtf(var + 1e-5f);

    #pragma unroll
    for (int j = 0; j < 3; ++j) {
        int c = tid + j * 256;
        y[base + c] = (v[j] - mu) * r * g_[c] + b_[c];
    }
}

// ---------------------------------------------------------------------------
extern "C" void kernel_launch(void* const* d_in, const int* in_sizes, int n_in,
                              void* d_out, int out_size, void* d_ws, size_t ws_size,
                              hipStream_t stream)
{
    const float* expanded = (const float*)d_in[0];
    const float* Wq = (const float*)d_in[1];
    const float* bq = (const float*)d_in[2];
    const float* Wk = (const float*)d_in[3];
    const float* bk = (const float*)d_in[4];
    const float* Wv = (const float*)d_in[5];
    const float* bv = (const float*)d_in[6];
    const float* Wo = (const float*)d_in[7];
    const float* bo = (const float*)d_in[8];
    const float* ln_g = (const float*)d_in[9];
    const float* ln_b = (const float*)d_in[10];
    float* out = (float*)d_out;

    char* ws = (char*)d_ws;
    const size_t WSZ = (size_t)D * D * sizeof(bf16);     // 1.18 MB
    bf16* WqkvT = (bf16*)(ws);                           // 3 slices
    bf16* WoT   = (bf16*)(ws + 3 * WSZ);
    const size_t fixed = 4 * WSZ;

    // Largest token-chunk fitting the workspace: Xb (768) + Qkv (2304) bf16/row.
    int cht = TP;
    while (cht > 128 && fixed + (size_t)cht * (D + NQKV) * sizeof(bf16) > ws_size)
        cht >>= 1;
    bf16* Xb  = (bf16*)(ws + fixed);
    bf16* Qkv = (bf16*)(ws + fixed + (size_t)cht * D * sizeof(bf16));

    k_transpose<<<dim3((D * D) / 256, 4), 256, 0, stream>>>(Wq, Wk, Wv, Wo, WqkvT, WoT);

    for (int t0 = 0; t0 < TP; t0 += cht) {
        k_prep<<<(cht * D) / 2048, 256, 0, stream>>>(expanded, Xb, t0);
        k_gemm_qkv<<<dim3(cht / 128, NQKV / 128), 256, 0, stream>>>(
            Xb, WqkvT, bq, bk, bv, Qkv);
        k_attn<<<dim3(cht / 128, NH), 256, 0, stream>>>(Qkv);
        k_oproj<<<dim3(cht / 128, D / 128), 256, 0, stream>>>(
            Qkv, WoT, bo, expanded, out, t0);
    }

    k_ln<<<BATCH * LSEQ, 256, 0, stream>>>(ln_g, ln_b, out);
}